// Round 7
// baseline (55.883 us; speedup 1.0000x reference)
//
#include <hip/hip_runtime.h>

// QueryAndGroup: ball_query(r=0.2, nsample=32) + group xyz (centered) + group features.
// B=4, N=16384, M=2048, C=64. Output (B, 67, M, 32) f32.
//
// R5 (36.8us) analysis: ~105MB HBM => 16.7us floor, +transpose ~6us => ~22us
// ideal; we're at 36.8 => latency/drain-bound, not BW-bound. Fixes:
//  1) Work-queue: 1024 blocks x 4 waves; each wave pulls queries (grain=1)
//     from 8 partitioned ticket counters (separate 64B lines) => no drain
//     tail from scan-length variance (corner queries scan ~5x the mean).
//  2) Gather preload: all 8 float4 of the sample's 256B featT row loaded to
//     registers before storing => the 4 line-misses overlap instead of
//     serializing behind stores.
// Everything else = R5: serial transpose kernel, per-wave prefetched scan,
// ballot/prefix-popcount selection, s-coalesced 128B stores.

#define WPB 4
constexpr int Bc = 4, Nc = 16384, Mc = 2048, Cc = 64, Sc = 32;
constexpr int NQ = Bc * Mc;          // 8192 queries
constexpr int NPART = 8;             // ticket partitions
constexpr int QPP = NQ / NPART;      // 1024 queries per partition
constexpr int QBLOCKS = 1024;        // 4096 waves -> avg 2 queries/wave

__global__ __launch_bounds__(256) void transpose_kernel(
    const float* __restrict__ feat,  // (B, C, N)
    float* __restrict__ featT)       // (B, N, C)
{
    __shared__ float tile[64][65];
    const int b = blockIdx.y;
    const int nbase = blockIdx.x * 64;
    const int tn = threadIdx.x & 63;
    const int tq = threadIdx.x >> 6;  // 0..3
    const float* fb = feat + (size_t)b * Cc * Nc;
    float* ob = featT + (size_t)b * Nc * Cc;
    #pragma unroll
    for (int k = 0; k < 16; ++k) {
        const int c = k * 4 + tq;
        tile[tn][c] = fb[(size_t)c * Nc + nbase + tn];      // coalesced reads
    }
    __syncthreads();
    #pragma unroll
    for (int k = 0; k < 16; ++k) {
        const int nl = k * 4 + tq;
        ob[(size_t)(nbase + nl) * Cc + tn] = tile[nl][tn];  // coalesced writes
    }
}

__global__ __launch_bounds__(256) void qg_kernel(
    const float* __restrict__ xyz,      // (B, N, 3)
    const float* __restrict__ new_xyz,  // (B, M, 3)
    const float* __restrict__ featT,    // (B, N, C)
    unsigned int* __restrict__ tick,    // 8 counters, 64B apart, zeroed
    float* __restrict__ out)            // (B, 67, M, 32)
{
#pragma clang fp contract(off)
    const int lane = threadIdx.x & 63;
    const int wv   = threadIdx.x >> 6;

    __shared__ int sidx[WPB][Sc];

    const float r2 = 0.2f * 0.2f;
    const unsigned long long lt = (1ull << lane) - 1ull;

    // Home partition: spread the block's 4 waves across partitions.
    const int p = ((blockIdx.x << 2) | wv) & (NPART - 1);
    unsigned int* cnt = tick + p * 16;   // 64B line spacing

    for (;;) {
        int t = 0;
        if (lane == 0) t = (int)atomicAdd(cnt, 1u);
        t = __shfl(t, 0);
        if (t >= QPP) return;            // partition drained (wave-uniform)
        const int q = p * QPP + t;
        const int b = q >> 11;           // / Mc
        const int m = q & (Mc - 1);

        const float* nz = new_xyz + (size_t)(b * Mc + m) * 3;
        const float qx = nz[0], qy = nz[1], qz = nz[2];
        const float* xb = xyz + (size_t)b * Nc * 3;

        int count = 0, firstIdx = 0;

        // Double-buffered scan: group k+1's 12 loads in flight while processing k.
        float px[4], py[4], pz[4];
        #pragma unroll
        for (int u = 0; u < 4; ++u) {
            const float* pp = xb + (size_t)(u * 64 + lane) * 3;
            px[u] = pp[0]; py[u] = pp[1]; pz[u] = pp[2];
        }
        for (int base = 0; base < Nc; base += 256) {
            const int nb = (base + 256 < Nc) ? base + 256 : base;   // clamped prefetch
            float nx[4], ny[4], nzv[4];
            #pragma unroll
            for (int u = 0; u < 4; ++u) {
                const float* pp = xb + (size_t)(nb + u * 64 + lane) * 3;
                nx[u] = pp[0]; ny[u] = pp[1]; nzv[u] = pp[2];
            }
            #pragma unroll
            for (int u = 0; u < 4; ++u) {
                const float dx = qx - px[u], dy = qy - py[u], dz = qz - pz[u];
                float d2 = dx * dx + dy * dy;   // no fma: match np/jax f32 rounding
                d2 = d2 + dz * dz;
                const bool in = d2 < r2;
                const unsigned long long mask = __ballot(in);
                if (in) {
                    const int slot = count + __popcll(mask & lt);
                    if (slot < Sc) sidx[wv][slot] = base + u * 64 + lane;
                }
                if (count == 0 && mask != 0ull)
                    firstIdx = base + u * 64 + __builtin_ctzll(mask);
                count += __popcll(mask);
            }
            if (count >= Sc) break;             // wave-uniform
            #pragma unroll
            for (int u = 0; u < 4; ++u) { px[u] = nx[u]; py[u] = ny[u]; pz[u] = nzv[u]; }
        }
        {
            const int start = count < Sc ? count : Sc;
            if (start + lane < Sc) sidx[wv][start + lane] = firstIdx;
        }
        // Same-wave LDS visibility only; waves stay decoupled.
        asm volatile("s_waitcnt lgkmcnt(0)" ::: "memory");

        const int s     = lane & 31;
        const int chalf = lane >> 5;
        const int myid  = sidx[wv][s];
        float* ob = out + ((size_t)b * 67 * Mc + m) * Sc;

        // Preload the whole 256B featT row (4 line-misses in flight together).
        const float* ftb = featT + ((size_t)b * Nc + myid) * Cc;
        float4 vr[8];
        #pragma unroll
        for (int it = 0; it < 8; ++it)
            vr[it] = *(const float4*)(ftb + (it * 2 + chalf) * 4);

        // Centered-xyz channels 0..2 (overlaps with featT misses).
        ob[(size_t)chalf * (Mc * Sc) + s] =
            xb[(size_t)myid * 3 + chalf] - (chalf ? qy : qx);
        if (chalf == 0)
            ob[(size_t)2 * (Mc * Sc) + s] = xb[(size_t)myid * 3 + 2] - qz;

        // Feature stores: 32 s-coalesced 128B-segment stores.
        #pragma unroll
        for (int it = 0; it < 8; ++it) {
            const int c4 = it * 2 + chalf;                  // 0..15
            #pragma unroll
            for (int k = 0; k < 4; ++k)
                ob[(size_t)(3 + c4 * 4 + k) * (Mc * Sc) + s] = ((const float*)&vr[it])[k];
        }
    }
}

// Fallback if ws too small: R5's static fused kernel with direct (C,N) gather.
__global__ __launch_bounds__(256) void qg_fallback_kernel(
    const float* __restrict__ xyz, const float* __restrict__ new_xyz,
    const float* __restrict__ feat, float* __restrict__ out)
{
#pragma clang fp contract(off)
    const int lane = threadIdx.x & 63;
    const int wv   = threadIdx.x >> 6;
    const int q    = blockIdx.x * WPB + wv;
    const int b    = q >> 11;
    const int m    = q & (Mc - 1);
    __shared__ int sidx[WPB][Sc];
    const float r2 = 0.2f * 0.2f;
    const float* nz = new_xyz + (size_t)(b * Mc + m) * 3;
    const float qx = nz[0], qy = nz[1], qz = nz[2];
    const float* xb = xyz + (size_t)b * Nc * 3;
    int count = 0, firstIdx = 0;
    const unsigned long long lt = (1ull << lane) - 1ull;
    for (int base = 0; base < Nc; base += 64) {
        const int i = base + lane;
        const float px = xb[i * 3], py = xb[i * 3 + 1], pz = xb[i * 3 + 2];
        const float dx = qx - px, dy = qy - py, dz = qz - pz;
        float d2 = dx * dx + dy * dy; d2 = d2 + dz * dz;
        const bool in = d2 < r2;
        const unsigned long long mask = __ballot(in);
        if (in) {
            const int slot = count + __popcll(mask & lt);
            if (slot < Sc) sidx[wv][slot] = i;
        }
        if (count == 0 && mask != 0ull) firstIdx = base + __builtin_ctzll(mask);
        count += __popcll(mask);
        if (count >= Sc) break;
    }
    const int start = count < Sc ? count : Sc;
    if (start + lane < Sc) sidx[wv][start + lane] = firstIdx;
    asm volatile("s_waitcnt lgkmcnt(0)" ::: "memory");
    const int s = lane & 31, chalf = lane >> 5;
    const int myid = sidx[wv][s];
    float* ob = out + ((size_t)b * 67 * Mc + m) * Sc;
    ob[(size_t)chalf * (Mc * Sc) + s] = xb[(size_t)myid * 3 + chalf] - (chalf ? qy : qx);
    if (chalf == 0)
        ob[(size_t)2 * (Mc * Sc) + s] = xb[(size_t)myid * 3 + 2] - qz;
    const float* fb = feat + (size_t)b * Cc * Nc;
    #pragma unroll
    for (int it = 0; it < 32; ++it) {
        const int c = it * 2 + chalf;
        ob[(size_t)(3 + c) * (Mc * Sc) + s] = fb[(size_t)c * Nc + myid];
    }
}

extern "C" void kernel_launch(void* const* d_in, const int* in_sizes, int n_in,
                              void* d_out, int out_size, void* d_ws, size_t ws_size,
                              hipStream_t stream) {
    const float* xyz     = (const float*)d_in[0];
    const float* new_xyz = (const float*)d_in[1];
    const float* feat    = (const float*)d_in[2];
    float* out           = (float*)d_out;

    const size_t featT_bytes = (size_t)Bc * Nc * Cc * sizeof(float);  // 16.8 MB
    const size_t tick_bytes  = 64 * NPART;                            // 512 B

    if (ws_size >= featT_bytes + tick_bytes) {
        float* featT = (float*)d_ws;
        unsigned int* tick = (unsigned int*)((char*)d_ws + featT_bytes);
        hipMemsetAsync(tick, 0, tick_bytes, stream);
        hipLaunchKernelGGL(transpose_kernel, dim3(Nc / 64, Bc), dim3(256), 0, stream,
                           feat, featT);
        hipLaunchKernelGGL(qg_kernel, dim3(QBLOCKS), dim3(256), 0, stream,
                           xyz, new_xyz, featT, tick, out);
    } else {
        hipLaunchKernelGGL(qg_fallback_kernel, dim3(NQ / WPB), dim3(256), 0, stream,
                           xyz, new_xyz, feat, out);
    }
}

// Round 8
// 38.807 us; speedup vs baseline: 1.4400x; 1.4400x over previous
//
#include <hip/hip_runtime.h>

// QueryAndGroup: ball_query(r=0.2, nsample=32) + group xyz (centered) + group features.
// B=4, N=16384, M=2048, C=64. Output (B, 67, M, 32) f32.
//
// History: R5 fused wave-per-query = 36.8us (best). R6 work-queue lost 8us by
// halving resident waves => occupancy is first-order. This round: cooperative
// block-per-query scan (4 waves x 64 pts per round) at full 32 waves/CU:
// per-query critical path and straggler tail shrink ~4x, block waves retire
// together. Selection = per-round ballot masks in LDS (parity double-buffer,
// one barrier/round) + cross-wave prefix popcount; first-32-by-index exact.
// Gather: thread (s,g) loads 2 independent float4 of featT row sidx[s];
// stores remain 128B-coalesced segments.

#define WPB 4
constexpr int Bc = 4, Nc = 16384, Mc = 2048, Cc = 64, Sc = 32;
constexpr int NQ = Bc * Mc;          // 8192 queries
constexpr int ROUNDS = Nc / 256;     // 64

__global__ __launch_bounds__(256) void transpose_kernel(
    const float* __restrict__ feat,  // (B, C, N)
    float* __restrict__ featT)       // (B, N, C)
{
    __shared__ float tile[64][65];
    const int b = blockIdx.y;
    const int nbase = blockIdx.x * 64;
    const int tn = threadIdx.x & 63;
    const int tq = threadIdx.x >> 6;  // 0..3
    const float* fb = feat + (size_t)b * Cc * Nc;
    float* ob = featT + (size_t)b * Nc * Cc;
    #pragma unroll
    for (int k = 0; k < 16; ++k) {
        const int c = k * 4 + tq;
        tile[tn][c] = fb[(size_t)c * Nc + nbase + tn];      // coalesced reads
    }
    __syncthreads();
    #pragma unroll
    for (int k = 0; k < 16; ++k) {
        const int nl = k * 4 + tq;
        ob[(size_t)(nbase + nl) * Cc + tn] = tile[nl][tn];  // coalesced writes
    }
}

__global__ __launch_bounds__(256) void coop_kernel(
    const float* __restrict__ xyz,      // (B, N, 3)
    const float* __restrict__ new_xyz,  // (B, M, 3)
    const float* __restrict__ featT,    // (B, N, C)
    float* __restrict__ out)            // (B, 67, M, 32)
{
#pragma clang fp contract(off)
    const int t    = threadIdx.x;
    const int lane = t & 63;
    const int wv   = t >> 6;
    const int q    = blockIdx.x;
    const int b    = q >> 11;            // / Mc
    const int m    = q & (Mc - 1);

    __shared__ unsigned long long wmask[2][4];   // parity double-buffered masks
    __shared__ int sidx[Sc];

    const float r2 = 0.2f * 0.2f;
    const float* nz = new_xyz + (size_t)(b * Mc + m) * 3;
    const float qx = nz[0], qy = nz[1], qz = nz[2];
    const float* xb = xyz + (size_t)b * Nc * 3;
    const unsigned long long lt = (1ull << lane) - 1ull;

    int count = 0;                        // uniform across the block
    float px, py, pz;
    {
        const float* pp = xb + (size_t)(wv * 64 + lane) * 3;
        px = pp[0]; py = pp[1]; pz = pp[2];
    }
    for (int r = 0;;) {
        // Prefetch next round's chunk (clamped; harmless reload on last).
        const int nr = (r + 1 < ROUNDS) ? r + 1 : r;
        const float* pp = xb + (size_t)(nr * 256 + wv * 64 + lane) * 3;
        const float nx = pp[0], ny = pp[1], nzz = pp[2];

        const float dx = qx - px, dy = qy - py, dz = qz - pz;
        float d2 = dx * dx + dy * dy;     // no fma: match np/jax f32 rounding
        d2 = d2 + dz * dz;
        const bool in = d2 < r2;
        const unsigned long long msk = __ballot(in);
        if (lane == 0) wmask[r & 1][wv] = msk;
        __syncthreads();
        const unsigned long long m0 = wmask[r & 1][0];
        const unsigned long long m1 = wmask[r & 1][1];
        const unsigned long long m2 = wmask[r & 1][2];
        const unsigned long long m3 = wmask[r & 1][3];

        int basew = count;                // slot base for this wave
        if (wv > 0) basew += __popcll(m0);
        if (wv > 1) basew += __popcll(m1);
        if (wv > 2) basew += __popcll(m2);
        if (in) {
            const int slot = basew + __popcll(msk & lt);
            if (slot < Sc) sidx[slot] = r * 256 + wv * 64 + lane;
        }
        count += __popcll(m0) + __popcll(m1) + __popcll(m2) + __popcll(m3);
        ++r;
        if (count >= Sc || r >= ROUNDS) break;   // block-uniform
        px = nx; py = ny; pz = nzz;
    }
    __syncthreads();                      // sidx visible block-wide
    {
        const int total = count < Sc ? count : Sc;
        const int first = (count > 0) ? sidx[0] : 0;   // sidx[0] valid iff count>0
        if (t >= total && t < Sc) sidx[t] = first;     // fill tail slots
    }
    __syncthreads();

    // ---- gather: thread (s = sample, g = channel-quad group) ----
    const int s = t & 31;
    const int g = t >> 5;                 // 0..7
    const int id = sidx[s];               // broadcast read (same addr per 8 thr)
    float* ob = out + ((size_t)b * 67 * Mc + m) * Sc;

    // Feature row: 2 independent float4 per thread (misses overlap).
    const float* row = featT + ((size_t)b * Nc + id) * Cc;
    const float4 v0 = *(const float4*)(row + g * 4);
    const float4 v1 = *(const float4*)(row + (g + 8) * 4);

    // Centered-xyz channels 0..2 (threads with g<3), overlaps with row misses.
    if (g < 3) {
        const float ctr = (g == 0) ? qx : (g == 1) ? qy : qz;
        ob[(size_t)g * (Mc * Sc) + s] = xb[(size_t)id * 3 + g] - ctr;
    }

    #pragma unroll
    for (int k = 0; k < 4; ++k) {
        ob[(size_t)(3 + g * 4 + k) * (Mc * Sc) + s]       = ((const float*)&v0)[k];
        ob[(size_t)(3 + (g + 8) * 4 + k) * (Mc * Sc) + s] = ((const float*)&v1)[k];
    }
}

// Fallback if ws too small: R5's static fused kernel with direct (C,N) gather.
__global__ __launch_bounds__(256) void qg_fallback_kernel(
    const float* __restrict__ xyz, const float* __restrict__ new_xyz,
    const float* __restrict__ feat, float* __restrict__ out)
{
#pragma clang fp contract(off)
    const int lane = threadIdx.x & 63;
    const int wv   = threadIdx.x >> 6;
    const int q    = blockIdx.x * WPB + wv;
    const int b    = q >> 11;
    const int m    = q & (Mc - 1);
    __shared__ int sidx[WPB][Sc];
    const float r2 = 0.2f * 0.2f;
    const float* nz = new_xyz + (size_t)(b * Mc + m) * 3;
    const float qx = nz[0], qy = nz[1], qz = nz[2];
    const float* xb = xyz + (size_t)b * Nc * 3;
    int count = 0, firstIdx = 0;
    const unsigned long long lt = (1ull << lane) - 1ull;
    for (int base = 0; base < Nc; base += 64) {
        const int i = base + lane;
        const float px = xb[i * 3], py = xb[i * 3 + 1], pz = xb[i * 3 + 2];
        const float dx = qx - px, dy = qy - py, dz = qz - pz;
        float d2 = dx * dx + dy * dy; d2 = d2 + dz * dz;
        const bool in = d2 < r2;
        const unsigned long long mask = __ballot(in);
        if (in) {
            const int slot = count + __popcll(mask & lt);
            if (slot < Sc) sidx[wv][slot] = i;
        }
        if (count == 0 && mask != 0ull) firstIdx = base + __builtin_ctzll(mask);
        count += __popcll(mask);
        if (count >= Sc) break;
    }
    const int start = count < Sc ? count : Sc;
    if (start + lane < Sc) sidx[wv][start + lane] = firstIdx;
    asm volatile("s_waitcnt lgkmcnt(0)" ::: "memory");
    const int s = lane & 31, chalf = lane >> 5;
    const int myid = sidx[wv][s];
    float* ob = out + ((size_t)b * 67 * Mc + m) * Sc;
    ob[(size_t)chalf * (Mc * Sc) + s] = xb[(size_t)myid * 3 + chalf] - (chalf ? qy : qx);
    if (chalf == 0)
        ob[(size_t)2 * (Mc * Sc) + s] = xb[(size_t)myid * 3 + 2] - qz;
    const float* fb = feat + (size_t)b * Cc * Nc;
    #pragma unroll
    for (int it = 0; it < 32; ++it) {
        const int c = it * 2 + chalf;
        ob[(size_t)(3 + c) * (Mc * Sc) + s] = fb[(size_t)c * Nc + myid];
    }
}

extern "C" void kernel_launch(void* const* d_in, const int* in_sizes, int n_in,
                              void* d_out, int out_size, void* d_ws, size_t ws_size,
                              hipStream_t stream) {
    const float* xyz     = (const float*)d_in[0];
    const float* new_xyz = (const float*)d_in[1];
    const float* feat    = (const float*)d_in[2];
    float* out           = (float*)d_out;

    const size_t featT_bytes = (size_t)Bc * Nc * Cc * sizeof(float);  // 16.8 MB

    if (ws_size >= featT_bytes) {
        float* featT = (float*)d_ws;
        hipLaunchKernelGGL(transpose_kernel, dim3(Nc / 64, Bc), dim3(256), 0, stream,
                           feat, featT);
        hipLaunchKernelGGL(coop_kernel, dim3(NQ), dim3(256), 0, stream,
                           xyz, new_xyz, featT, out);
    } else {
        hipLaunchKernelGGL(qg_fallback_kernel, dim3(NQ / WPB), dim3(256), 0, stream,
                           xyz, new_xyz, feat, out);
    }
}